// Round 5
// baseline (518.607 us; speedup 1.0000x reference)
//
#include <hip/hip_runtime.h>
#include <cstdint>
#include <cstddef>

typedef unsigned short u16;
typedef __bf16 bf16_t;
typedef bf16_t bf16x8 __attribute__((ext_vector_type(8)));
typedef float f32x4 __attribute__((ext_vector_type(4)));

__device__ __forceinline__ u16 f32_to_bf16(float f) {
  uint32_t u = __builtin_bit_cast(uint32_t, f);
  u += 0x7fffu + ((u >> 16) & 1u);   // RNE
  return (u16)(u >> 16);
}

// pack two f32 -> two bf16 in one u32 (round-half-up + v_perm_b32)
__device__ __forceinline__ uint32_t pack_bf16x2(float lo, float hi) {
  uint32_t a = __builtin_bit_cast(uint32_t, hi) + 0x8000u;
  uint32_t b = __builtin_bit_cast(uint32_t, lo) + 0x8000u;
  return __builtin_amdgcn_perm(a, b, 0x07060302u);
}

// async global->LDS, 16B per lane. LDS dest is wave-uniform base; HW adds lane*16.
__device__ __forceinline__ void gload_lds16(const void* g, void* l) {
  __builtin_amdgcn_global_load_lds(
      (const __attribute__((address_space(1))) unsigned int*)g,
      (__attribute__((address_space(3))) unsigned int*)l, 16, 0, 0);
}

// Barrier WITHOUT the compiler's vmcnt(0) drain: drains only LDS ops, leaves
// global prefetch loads in flight (m139 technique).
__device__ __forceinline__ void lgkm_barrier() {
  asm volatile("s_waitcnt lgkmcnt(0)\n\ts_barrier" ::: "memory");
}

// ---------------- fp32 -> bf16 elementwise convert ----------------
__global__ void cvt_bf16(const float* __restrict__ in, u16* __restrict__ out, int n) {
  int i = (blockIdx.x * 256 + threadIdx.x) * 4;
  if (i < n) {
    float4 f = *(const float4*)(in + i);
    ushort4 o;
    o.x = f32_to_bf16(f.x); o.y = f32_to_bf16(f.y);
    o.z = f32_to_bf16(f.z); o.w = f32_to_bf16(f.w);
    *(ushort4*)(out + i) = o;
  }
}

// ---------------- fp32 [R][C] -> bf16 [C][R] transpose-convert ----------------
__global__ void tconv(const float* __restrict__ in, u16* __restrict__ out, int R, int C) {
  __shared__ u16 t[64][80];
  int tid = threadIdx.x;
  int cb = blockIdx.x * 64, rb = blockIdx.y * 64;
  int rr = tid >> 2, cg = (tid & 3) * 16;
  const float* ip = in + (size_t)(rb + rr) * C + cb + cg;
#pragma unroll
  for (int i = 0; i < 16; ++i) t[rr][cg + i] = f32_to_bf16(ip[i]);
  __syncthreads();
  int cc = tid >> 2, rg = (tid & 3) * 16;
  u16* op = out + (size_t)(cb + cc) * R + rb + rg;
  union { uint4 v[2]; u16 s[16]; } tmp;
#pragma unroll
  for (int i = 0; i < 16; ++i) tmp.s[i] = t[rg + i][cc];
  *(uint4*)op = tmp.v[0];
  *(uint4*)(op + 8) = tmp.v[1];
}

// ---------------- V slice of qkv (bf16) -> Vt [bh][d=64][t=2048] ----------------
__global__ void vtrans(const u16* __restrict__ qkvb, u16* __restrict__ vt) {
  __shared__ u16 t[64][80];
  int tid = threadIdx.x;
  int bh = blockIdx.x, tb = blockIdx.y * 64;
  int b = bh >> 4, h = bh & 15;
  int tt = tid >> 2, dg = (tid & 3) * 16;
  const u16* ip = qkvb + (size_t)(b * 2048 + tb + tt) * 3072 + 2048 + h * 64 + dg;
  union { uint4 v; u16 s[8]; } a0, a1;
  a0.v = *(const uint4*)ip;
  a1.v = *(const uint4*)(ip + 8);
#pragma unroll
  for (int i = 0; i < 8; ++i) { t[tt][dg + i] = a0.s[i]; t[tt][dg + 8 + i] = a1.s[i]; }
  __syncthreads();
  int dd = tid >> 2, tg = (tid & 3) * 16;
  u16* op = vt + (size_t)(bh * 64 + dd) * 2048 + tb + tg;
  union { uint4 v[2]; u16 s[16]; } tmp;
#pragma unroll
  for (int i = 0; i < 16; ++i) tmp.s[i] = t[tg + i][dd];
  *(uint4*)op = tmp.v[0];
  *(uint4*)(op + 8) = tmp.v[1];
}

// ---------------- bf16 GEMM: C[M,N] = A[M,K] * Bt[N,K]^T + bias ----------------
// 128x128x64 tile, 4 waves. Register-prefetch pipeline: tile k+1 is loaded
// global->VGPR while tile k is MFMA'd from the single LDS buffer, then written
// via conflict-free ds_write_b128. Barriers are raw lgkmcnt(0)+s_barrier so
// prefetch loads stay in flight across them.
// launch_bounds(256,2): ~256 unified regs/wave so acc(64 AGPR)+pref(32)+arch
// all fit — (256,3) spilled pref to scratch (R3: 762 MB scratch writes).
template <int OUT_BF16>
__global__ __launch_bounds__(256, 2) void gemm_bt(const u16* __restrict__ A,
                                                  const u16* __restrict__ Bt,
                                                  const float* __restrict__ bias,
                                                  void* __restrict__ Cout,
                                                  int M, int N, int K) {
  __shared__ __align__(16) u16 sA[16 * 512];
  __shared__ __align__(16) u16 sB[16 * 512];
  const int tid = threadIdx.x;
  const int w = tid >> 6, L = tid & 63;
  const int quad = L >> 4, lc = L & 15;
  const int tileM = blockIdx.y * 128;
  const int tileN = blockIdx.x * 128;
  const int wr = w >> 1, wc = w & 1;

  // per-thread staging slots: fb = w*8 + i; identical addressing to the
  // global_load_lds fragment layout (lane's 16B at frag*1KB + L*16B).
  const u16* gptr[8];
  u16* lptr[8];
#pragma unroll
  for (int i = 0; i < 8; ++i) {
    int fb = w * 8 + i;
    if (fb < 16) {
      gptr[i] = A + (size_t)(tileM + (fb >> 1) * 16 + lc) * K + (fb & 1) * 32 + quad * 8;
      lptr[i] = &sA[fb * 512 + L * 8];
    } else {
      int f = fb - 16;
      gptr[i] = Bt + (size_t)(tileN + (f >> 1) * 16 + lc) * K + (f & 1) * 32 + quad * 8;
      lptr[i] = &sB[f * 512 + L * 8];
    }
  }

  f32x4 acc[4][4] = {};

  // prologue: stage tile 0 via async global_load_lds (wave-uniform LDS base)
#pragma unroll
  for (int i = 0; i < 8; ++i) {
    int fb = w * 8 + i;
    u16* lbase = (fb < 16) ? &sA[fb * 512] : &sB[(fb - 16) * 512];
    gload_lds16(gptr[i], lbase);
  }
  __syncthreads();  // full drain, prologue only

  for (int kk = 0; kk < K; kk += 64) {
    const bool more = (kk + 64) < K;
    uint4 pref[8];
    if (more) {
#pragma unroll
      for (int i = 0; i < 8; ++i)
        pref[i] = *(const uint4*)(gptr[i] + kk + 64);
    }
    // compute on current tile (in LDS)
#pragma unroll
    for (int ks = 0; ks < 2; ++ks) {
      bf16x8 af[4], bfr[4];
#pragma unroll
      for (int t = 0; t < 4; ++t)
        af[t] = *(const bf16x8*)&sA[((wr * 4 + t) * 2 + ks) * 512 + L * 8];
#pragma unroll
      for (int t = 0; t < 4; ++t)
        bfr[t] = *(const bf16x8*)&sB[((wc * 4 + t) * 2 + ks) * 512 + L * 8];
#pragma unroll
      for (int mi = 0; mi < 4; ++mi)
#pragma unroll
        for (int ni = 0; ni < 4; ++ni)
          acc[mi][ni] = __builtin_amdgcn_mfma_f32_16x16x32_bf16(af[mi], bfr[ni], acc[mi][ni], 0, 0, 0);
    }
    if (more) {
      lgkm_barrier();  // all waves done reading sA/sB; prefetch still in flight
#pragma unroll
      for (int i = 0; i < 8; ++i)
        *(uint4*)lptr[i] = pref[i];  // vmcnt wait lands here, after the MFMAs
      lgkm_barrier();  // staged tile visible to all waves
    }
  }

#pragma unroll
  for (int mi = 0; mi < 4; ++mi) {
    int rowb = tileM + wr * 64 + mi * 16 + quad * 4;
#pragma unroll
    for (int ni = 0; ni < 4; ++ni) {
      int col = tileN + wc * 64 + ni * 16 + lc;
      float bv = bias[col];
#pragma unroll
      for (int r = 0; r < 4; ++r) {
        float v = acc[mi][ni][r] + bv;
        if (OUT_BF16)
          ((u16*)Cout)[(size_t)(rowb + r) * N + col] = f32_to_bf16(v);
        else
          ((float*)Cout)[(size_t)(rowb + r) * N + col] = v;
      }
    }
  }
}

// ---------------- causal flash attention, S^T formulation ----------------
// S^T = K·Q^T  (A=K frag, B=Q frag) -> C-layout: row=tk, col=q(lc).
// O^T = V^T·P (A=V^T frag, B=P frag). Softmax sum l is per-lane (col=q).
// Fixed-max softmax; diagonal-only masking; paired qt for uniform work.
__global__ __launch_bounds__(256, 4) void attn(const u16* __restrict__ qkvb,
                                               const u16* __restrict__ vt,
                                               u16* __restrict__ yb) {
  __shared__ __align__(16) u16 kbuf[8 * 512];
  __shared__ __align__(16) u16 vbuf[8 * 512];
  __shared__ __align__(16) u16 pbuf[4][1024];  // per-wave, frag order [ks][lane][8]
  const int tid = threadIdx.x;
  const int w = tid >> 6, L = tid & 63;
  const int quad = L >> 4, lc = L & 15;
  const int bh = blockIdx.x;
  const int b = bh >> 4, h = bh & 15;
  const int pair = blockIdx.y;
  const float e_c = 0.18033688f;  // (1/sqrt(64)) * log2(e)
  u16* pb = (u16*)pbuf[w];

  for (int pass = 0; pass < 2; ++pass) {
    const int qt = pass ? (31 - pair) : pair;
    const int qbase = qt * 64;
    const int q_loc = w * 16 + lc;

    bf16x8 qf[2];
    {
      const u16* qp = qkvb + ((size_t)(b * 2048 + qbase + q_loc) * 3072 + h * 64 + quad * 8);
      qf[0] = *(const bf16x8*)qp;
      qf[1] = *(const bf16x8*)(qp + 32);
    }
    f32x4 o[4] = {};
    float lsum = 0.f;

    for (int kb = 0; kb <= qbase; kb += 64) {
      const bool diag = (kb == qbase);
      __syncthreads();
#pragma unroll
      for (int i = 0; i < 4; ++i) {
        int fb = w * 4 + i;  // wave-uniform
        if (fb < 8) {        // K tile, A-operand of K·Q^T (m=tk, k=d)
          int nt = fb >> 1, ks = fb & 1;
          int tk = kb + nt * 16 + lc;
          int d = ks * 32 + quad * 8;
          gload_lds16(qkvb + ((size_t)(b * 2048 + tk) * 3072 + 1024 + h * 64 + d), &kbuf[fb * 512]);
        } else {             // V^T tile, A-operand of V^T·P (m=d, k=tk)
          int f = fb - 8;
          int dt = f >> 1, ks = f & 1;
          int d = dt * 16 + lc;
          int tk = kb + ks * 32 + quad * 8;
          gload_lds16(vt + ((size_t)(bh * 64 + d) * 2048 + tk), &vbuf[f * 512]);
        }
      }
      __syncthreads();

      // S^T[tk][q]
      f32x4 s[4];
#pragma unroll
      for (int nt = 0; nt < 4; ++nt) {
        s[nt] = (f32x4){0.f, 0.f, 0.f, 0.f};
#pragma unroll
        for (int ks = 0; ks < 2; ++ks) {
          bf16x8 kf = *(const bf16x8*)&kbuf[(nt * 2 + ks) * 512 + L * 8];
          s[nt] = __builtin_amdgcn_mfma_f32_16x16x32_bf16(kf, qf[ks], s[nt], 0, 0, 0);
        }
      }

      // p = exp2(s*e_c); mask diagonal; accumulate per-lane l; pack to pbuf
#pragma unroll
      for (int nt = 0; nt < 4; ++nt) {
        float p0 = __builtin_amdgcn_exp2f(s[nt][0] * e_c);
        float p1 = __builtin_amdgcn_exp2f(s[nt][1] * e_c);
        float p2 = __builtin_amdgcn_exp2f(s[nt][2] * e_c);
        float p3 = __builtin_amdgcn_exp2f(s[nt][3] * e_c);
        if (diag) {
          int tk0 = nt * 16 + quad * 4;
          p0 = (tk0 + 0 > q_loc) ? 0.f : p0;
          p1 = (tk0 + 1 > q_loc) ? 0.f : p1;
          p2 = (tk0 + 2 > q_loc) ? 0.f : p2;
          p3 = (tk0 + 3 > q_loc) ? 0.f : p3;
        }
        lsum += (p0 + p1) + (p2 + p3);
        uint2 pk;
        pk.x = pack_bf16x2(p0, p1);
        pk.y = pack_bf16x2(p2, p3);
        int idx = (nt >> 1) * 512 + (((nt & 1) * 2 + (quad >> 1)) * 16 + lc) * 8 + (quad & 1) * 4;
        *(uint2*)&pb[idx] = pk;
      }

      // O^T += V^T · P
#pragma unroll
      for (int ks = 0; ks < 2; ++ks) {
        bf16x8 pf = *(const bf16x8*)&pb[ks * 512 + L * 8];
#pragma unroll
        for (int dt = 0; dt < 4; ++dt) {
          bf16x8 vf = *(const bf16x8*)&vbuf[(dt * 2 + ks) * 512 + L * 8];
          o[dt] = __builtin_amdgcn_mfma_f32_16x16x32_bf16(vf, pf, o[dt], 0, 0, 0);
        }
      }
    }

    // l: sum the 4 quad partials for column q=lc
    lsum += __shfl_xor(lsum, 16);
    lsum += __shfl_xor(lsum, 32);
    float inv = 1.f / lsum;

    // store y[t=qbase+q_loc][h*64 + d], lane holds d = dt*16 + quad*4 + r
    {
      u16* yp = yb + (size_t)(b * 2048 + qbase + q_loc) * 1024 + h * 64 + quad * 4;
#pragma unroll
      for (int dt = 0; dt < 4; ++dt) {
        uint2 pk;
        pk.x = pack_bf16x2(o[dt][0] * inv, o[dt][1] * inv);
        pk.y = pack_bf16x2(o[dt][2] * inv, o[dt][3] * inv);
        *(uint2*)(yp + dt * 16) = pk;
      }
    }
  }
}

extern "C" void kernel_launch(void* const* d_in, const int* in_sizes, int n_in,
                              void* d_out, int out_size, void* d_ws, size_t ws_size,
                              hipStream_t stream) {
  const float* x = (const float*)d_in[0];
  const float* w_attn = (const float*)d_in[1];
  const float* b_attn = (const float*)d_in[2];
  const float* w_proj = (const float*)d_in[3];
  const float* b_proj = (const float*)d_in[4];
  float* out = (float*)d_out;

  char* ws = (char*)d_ws;
  u16* xb = (u16*)ws;    ws += (size_t)8192 * 1024 * 2;
  u16* waT = (u16*)ws;   ws += (size_t)3072 * 1024 * 2;
  u16* wpT = (u16*)ws;   ws += (size_t)1024 * 1024 * 2;
  u16* qkvb = (u16*)ws;  ws += (size_t)8192 * 3072 * 2;
  u16* vtb = (u16*)ws;   ws += (size_t)64 * 64 * 2048 * 2;
  u16* yb = (u16*)ws;    ws += (size_t)8192 * 1024 * 2;

  cvt_bf16<<<8192, 256, 0, stream>>>(x, xb, 8192 * 1024);
  tconv<<<dim3(3072 / 64, 1024 / 64), 256, 0, stream>>>(w_attn, waT, 1024, 3072);
  tconv<<<dim3(1024 / 64, 1024 / 64), 256, 0, stream>>>(w_proj, wpT, 1024, 1024);
  gemm_bt<1><<<dim3(3072 / 128, 8192 / 128), 256, 0, stream>>>(xb, waT, b_attn, qkvb, 8192, 3072, 1024);
  vtrans<<<dim3(64, 32), 256, 0, stream>>>(qkvb, vtb);
  attn<<<dim3(64, 16), 256, 0, stream>>>(qkvb, vtb, yb);
  gemm_bt<0><<<dim3(1024 / 128, 8192 / 128), 256, 0, stream>>>(yb, wpT, b_proj, out, 8192, 1024, 1024);
}

// Round 6
// 318.004 us; speedup vs baseline: 1.6308x; 1.6308x over previous
//
#include <hip/hip_runtime.h>
#include <cstdint>
#include <cstddef>

typedef unsigned short u16;
typedef __bf16 bf16_t;
typedef bf16_t bf16x8 __attribute__((ext_vector_type(8)));
typedef float f32x4 __attribute__((ext_vector_type(4)));

__device__ __forceinline__ u16 f32_to_bf16(float f) {
  uint32_t u = __builtin_bit_cast(uint32_t, f);
  u += 0x7fffu + ((u >> 16) & 1u);   // RNE
  return (u16)(u >> 16);
}

// pack two f32 -> two bf16 in one u32 (round-half-up + v_perm_b32)
__device__ __forceinline__ uint32_t pack_bf16x2(float lo, float hi) {
  uint32_t a = __builtin_bit_cast(uint32_t, hi) + 0x8000u;
  uint32_t b = __builtin_bit_cast(uint32_t, lo) + 0x8000u;
  return __builtin_amdgcn_perm(a, b, 0x07060302u);
}

// async global->LDS, 16B per lane. LDS dest is wave-uniform base; HW adds lane*16.
__device__ __forceinline__ void gload_lds16(const void* g, void* l) {
  __builtin_amdgcn_global_load_lds(
      (const __attribute__((address_space(1))) unsigned int*)g,
      (__attribute__((address_space(3))) unsigned int*)l, 16, 0, 0);
}

// hand-rolled pipeline barrier: wait for my DMA loads (vmcnt) + my LDS ops
// (lgkm, usually already 0), then barrier. No compiler-inserted drain before.
__device__ __forceinline__ void vm_barrier() {
  asm volatile("s_waitcnt vmcnt(0) lgkmcnt(0)\n\ts_barrier" ::: "memory");
}

// ---------------- fp32 -> bf16 elementwise convert ----------------
__global__ void cvt_bf16(const float* __restrict__ in, u16* __restrict__ out, int n) {
  int i = (blockIdx.x * 256 + threadIdx.x) * 4;
  if (i < n) {
    float4 f = *(const float4*)(in + i);
    ushort4 o;
    o.x = f32_to_bf16(f.x); o.y = f32_to_bf16(f.y);
    o.z = f32_to_bf16(f.z); o.w = f32_to_bf16(f.w);
    *(ushort4*)(out + i) = o;
  }
}

// ---------------- fp32 [R][C] -> bf16 [C][R] transpose-convert ----------------
__global__ void tconv(const float* __restrict__ in, u16* __restrict__ out, int R, int C) {
  __shared__ u16 t[64][80];
  int tid = threadIdx.x;
  int cb = blockIdx.x * 64, rb = blockIdx.y * 64;
  int rr = tid >> 2, cg = (tid & 3) * 16;
  const float* ip = in + (size_t)(rb + rr) * C + cb + cg;
#pragma unroll
  for (int i = 0; i < 16; ++i) t[rr][cg + i] = f32_to_bf16(ip[i]);
  __syncthreads();
  int cc = tid >> 2, rg = (tid & 3) * 16;
  u16* op = out + (size_t)(cb + cc) * R + rb + rg;
  union { uint4 v[2]; u16 s[16]; } tmp;
#pragma unroll
  for (int i = 0; i < 16; ++i) tmp.s[i] = t[rg + i][cc];
  *(uint4*)op = tmp.v[0];
  *(uint4*)(op + 8) = tmp.v[1];
}

// ---------------- V slice of qkv (bf16) -> Vt [bh][d=64][t=2048] ----------------
__global__ void vtrans(const u16* __restrict__ qkvb, u16* __restrict__ vt) {
  __shared__ u16 t[64][80];
  int tid = threadIdx.x;
  int bh = blockIdx.x, tb = blockIdx.y * 64;
  int b = bh >> 4, h = bh & 15;
  int tt = tid >> 2, dg = (tid & 3) * 16;
  const u16* ip = qkvb + (size_t)(b * 2048 + tb + tt) * 3072 + 2048 + h * 64 + dg;
  union { uint4 v; u16 s[8]; } a0, a1;
  a0.v = *(const uint4*)ip;
  a1.v = *(const uint4*)(ip + 8);
#pragma unroll
  for (int i = 0; i < 8; ++i) { t[tt][dg + i] = a0.s[i]; t[tt][dg + 8 + i] = a1.s[i]; }
  __syncthreads();
  int dd = tid >> 2, tg = (tid & 3) * 16;
  u16* op = vt + (size_t)(bh * 64 + dd) * 2048 + tb + tg;
  union { uint4 v[2]; u16 s[16]; } tmp;
#pragma unroll
  for (int i = 0; i < 16; ++i) tmp.s[i] = t[tg + i][dd];
  *(uint4*)op = tmp.v[0];
  *(uint4*)(op + 8) = tmp.v[1];
}

// ---------------- bf16 GEMM: C[M,N] = A[M,K] * Bt[N,K]^T + bias ----------------
// 128x128x64 tile, 4 waves. DOUBLE-BUFFERED LDS pipeline with global_load_lds:
// per iter, issue 8 DMA loads for tile k+1 into buf^1, run 32 MFMAs from buf,
// then vmcnt(0)+barrier (hand-rolled — no __syncthreads in the loop, so the
// load latency overlaps the MFMA section instead of stalling at the barrier).
// Zero prefetch VGPRs -> nothing for the allocator to spill (R3/R5 lesson).
// frag layout: frags 0..15 = A, 16..31 = B; frag fb at sAB[buf][fb*512].
template <int OUT_BF16>
__global__ __launch_bounds__(256, 2) void gemm_bt(const u16* __restrict__ A,
                                                  const u16* __restrict__ Bt,
                                                  const float* __restrict__ bias,
                                                  void* __restrict__ Cout,
                                                  int M, int N, int K) {
  __shared__ __align__(16) u16 sAB[2][32 * 512];  // 64 KB
  const int tid = threadIdx.x;
  const int w = tid >> 6, L = tid & 63;
  const int quad = L >> 4, lc = L & 15;
  const int tileM = blockIdx.y * 128;
  const int tileN = blockIdx.x * 128;
  const int wr = w >> 1, wc = w & 1;

  // this thread's 8 staging fragments (fb = w*8+i): global source pointers
  const u16* gptr[8];
#pragma unroll
  for (int i = 0; i < 8; ++i) {
    int fb = w * 8 + i;
    if (fb < 16)
      gptr[i] = A + (size_t)(tileM + (fb >> 1) * 16 + lc) * K + (fb & 1) * 32 + quad * 8;
    else {
      int f = fb - 16;
      gptr[i] = Bt + (size_t)(tileN + (f >> 1) * 16 + lc) * K + (f & 1) * 32 + quad * 8;
    }
  }

  f32x4 acc[4][4] = {};

  // prologue: stage tile 0 into buf 0
#pragma unroll
  for (int i = 0; i < 8; ++i)
    gload_lds16(gptr[i], &sAB[0][(w * 8 + i) * 512]);
  vm_barrier();

  int cur = 0;
  for (int kk = 0; kk < K; kk += 64) {
    const bool more = (kk + 64) < K;
    if (more) {
#pragma unroll
      for (int i = 0; i < 8; ++i)
        gload_lds16(gptr[i] + kk + 64, &sAB[cur ^ 1][(w * 8 + i) * 512]);
    }
    const u16* base = sAB[cur];
#pragma unroll
    for (int ks = 0; ks < 2; ++ks) {
      bf16x8 af[4], bfr[4];
#pragma unroll
      for (int t = 0; t < 4; ++t)
        af[t] = *(const bf16x8*)&base[(((wr * 4 + t) * 2 + ks)) * 512 + L * 8];
#pragma unroll
      for (int t = 0; t < 4; ++t)
        bfr[t] = *(const bf16x8*)&base[((16 + (wc * 4 + t) * 2 + ks)) * 512 + L * 8];
#pragma unroll
      for (int mi = 0; mi < 4; ++mi)
#pragma unroll
        for (int ni = 0; ni < 4; ++ni)
          acc[mi][ni] = __builtin_amdgcn_mfma_f32_16x16x32_bf16(af[mi], bfr[ni], acc[mi][ni], 0, 0, 0);
    }
    if (more) {
      vm_barrier();  // tile k+1 landed everywhere; everyone done reading buf
      cur ^= 1;
    }
  }

#pragma unroll
  for (int mi = 0; mi < 4; ++mi) {
    int rowb = tileM + wr * 64 + mi * 16 + quad * 4;
#pragma unroll
    for (int ni = 0; ni < 4; ++ni) {
      int col = tileN + wc * 64 + ni * 16 + lc;
      float bv = bias[col];
#pragma unroll
      for (int r = 0; r < 4; ++r) {
        float v = acc[mi][ni][r] + bv;
        if (OUT_BF16)
          ((u16*)Cout)[(size_t)(rowb + r) * N + col] = f32_to_bf16(v);
        else
          ((float*)Cout)[(size_t)(rowb + r) * N + col] = v;
      }
    }
  }
}

// ---------------- causal flash attention, S^T formulation ----------------
// S^T = K·Q^T (A=K frag, B=Q frag) -> C-layout row=tk, col=q(lc).
// O^T = V^T·P. Per-lane softmax sum; fixed-max softmax; diagonal-only mask;
// paired qt for uniform work. K/V tiles double-buffered with the same
// vmcnt-barrier pipeline as gemm_bt. frags 0..7 = K, 8..15 = V^T.
__global__ __launch_bounds__(256, 4) void attn(const u16* __restrict__ qkvb,
                                               const u16* __restrict__ vt,
                                               u16* __restrict__ yb) {
  __shared__ __align__(16) u16 kv[2][16 * 512];   // 32 KB
  __shared__ __align__(16) u16 pbuf[4][1024];     // 8 KB, per-wave P frags
  const int tid = threadIdx.x;
  const int w = tid >> 6, L = tid & 63;
  const int quad = L >> 4, lc = L & 15;
  const int bh = blockIdx.x;
  const int b = bh >> 4, h = bh & 15;
  const int pair = blockIdx.y;
  const float e_c = 0.18033688f;  // (1/sqrt(64)) * log2(e)
  u16* pb = (u16*)pbuf[w];

  // this thread's 4 staging fragments (fb = w*4+i): global source address
  // as a function of kb.
  const int fb0 = w * 4;

  for (int pass = 0; pass < 2; ++pass) {
    const int qt = pass ? (31 - pair) : pair;
    const int qbase = qt * 64;
    const int q_loc = w * 16 + lc;

    bf16x8 qf[2];
    {
      const u16* qp = qkvb + ((size_t)(b * 2048 + qbase + q_loc) * 3072 + h * 64 + quad * 8);
      qf[0] = *(const bf16x8*)qp;
      qf[1] = *(const bf16x8*)(qp + 32);
    }
    f32x4 o[4] = {};
    float lsum = 0.f;

    __syncthreads();  // pass boundary: everyone done reading kv from prior pass
    // prologue: stage kb=0 into buf 0
#pragma unroll
    for (int i = 0; i < 4; ++i) {
      int fb = fb0 + i;
      if (fb < 8)
        gload_lds16(qkvb + ((size_t)(b * 2048 + (fb >> 1) * 16 + lc) * 3072 + 1024 + h * 64 + (fb & 1) * 32 + quad * 8),
                    &kv[0][fb * 512]);
      else {
        int f = fb - 8;
        gload_lds16(vt + ((size_t)(bh * 64 + (f >> 1) * 16 + lc) * 2048 + (f & 1) * 32 + quad * 8),
                    &kv[0][fb * 512]);
      }
    }
    vm_barrier();

    int cur = 0;
    for (int kb = 0; kb <= qbase; kb += 64) {
      const bool diag = (kb == qbase);
      const bool more = (kb + 64) <= qbase;
      if (more) {
        int kn = kb + 64;
#pragma unroll
        for (int i = 0; i < 4; ++i) {
          int fb = fb0 + i;
          if (fb < 8)
            gload_lds16(qkvb + ((size_t)(b * 2048 + kn + (fb >> 1) * 16 + lc) * 3072 + 1024 + h * 64 + (fb & 1) * 32 + quad * 8),
                        &kv[cur ^ 1][fb * 512]);
          else {
            int f = fb - 8;
            gload_lds16(vt + ((size_t)(bh * 64 + (f >> 1) * 16 + lc) * 2048 + kn + (f & 1) * 32 + quad * 8),
                        &kv[cur ^ 1][f * 512 + 8 * 512]);
          }
        }
      }
      const u16* base = kv[cur];

      // S^T[tk][q]
      f32x4 s[4];
#pragma unroll
      for (int nt = 0; nt < 4; ++nt) {
        s[nt] = (f32x4){0.f, 0.f, 0.f, 0.f};
#pragma unroll
        for (int ks = 0; ks < 2; ++ks) {
          bf16x8 kf = *(const bf16x8*)&base[(nt * 2 + ks) * 512 + L * 8];
          s[nt] = __builtin_amdgcn_mfma_f32_16x16x32_bf16(kf, qf[ks], s[nt], 0, 0, 0);
        }
      }

      // p = exp2(s*e_c); mask diagonal; accumulate per-lane l; pack to pbuf
#pragma unroll
      for (int nt = 0; nt < 4; ++nt) {
        float p0 = __builtin_amdgcn_exp2f(s[nt][0] * e_c);
        float p1 = __builtin_amdgcn_exp2f(s[nt][1] * e_c);
        float p2 = __builtin_amdgcn_exp2f(s[nt][2] * e_c);
        float p3 = __builtin_amdgcn_exp2f(s[nt][3] * e_c);
        if (diag) {
          int tk0 = nt * 16 + quad * 4;
          p0 = (tk0 + 0 > q_loc) ? 0.f : p0;
          p1 = (tk0 + 1 > q_loc) ? 0.f : p1;
          p2 = (tk0 + 2 > q_loc) ? 0.f : p2;
          p3 = (tk0 + 3 > q_loc) ? 0.f : p3;
        }
        lsum += (p0 + p1) + (p2 + p3);
        uint2 pk;
        pk.x = pack_bf16x2(p0, p1);
        pk.y = pack_bf16x2(p2, p3);
        int idx = (nt >> 1) * 512 + (((nt & 1) * 2 + (quad >> 1)) * 16 + lc) * 8 + (quad & 1) * 4;
        *(uint2*)&pb[idx] = pk;
      }

      // O^T += V^T · P
#pragma unroll
      for (int ks = 0; ks < 2; ++ks) {
        bf16x8 pf = *(const bf16x8*)&pb[ks * 512 + L * 8];
#pragma unroll
        for (int dt = 0; dt < 4; ++dt) {
          bf16x8 vf = *(const bf16x8*)&base[(8 + dt * 2 + ks) * 512 + L * 8];
          o[dt] = __builtin_amdgcn_mfma_f32_16x16x32_bf16(vf, pf, o[dt], 0, 0, 0);
        }
      }

      if (more) {
        vm_barrier();
        cur ^= 1;
      }
    }

    // l: sum the 4 quad partials for column q=lc
    lsum += __shfl_xor(lsum, 16);
    lsum += __shfl_xor(lsum, 32);
    float inv = 1.f / lsum;

    // store y[t=qbase+q_loc][h*64 + d], lane holds d = dt*16 + quad*4 + r
    {
      u16* yp = yb + (size_t)(b * 2048 + qbase + q_loc) * 1024 + h * 64 + quad * 4;
#pragma unroll
      for (int dt = 0; dt < 4; ++dt) {
        uint2 pk;
        pk.x = pack_bf16x2(o[dt][0] * inv, o[dt][1] * inv);
        pk.y = pack_bf16x2(o[dt][2] * inv, o[dt][3] * inv);
        *(uint2*)(yp + dt * 16) = pk;
      }
    }
  }
}

extern "C" void kernel_launch(void* const* d_in, const int* in_sizes, int n_in,
                              void* d_out, int out_size, void* d_ws, size_t ws_size,
                              hipStream_t stream) {
  const float* x = (const float*)d_in[0];
  const float* w_attn = (const float*)d_in[1];
  const float* b_attn = (const float*)d_in[2];
  const float* w_proj = (const float*)d_in[3];
  const float* b_proj = (const float*)d_in[4];
  float* out = (float*)d_out;

  char* ws = (char*)d_ws;
  u16* xb = (u16*)ws;    ws += (size_t)8192 * 1024 * 2;
  u16* waT = (u16*)ws;   ws += (size_t)3072 * 1024 * 2;
  u16* wpT = (u16*)ws;   ws += (size_t)1024 * 1024 * 2;
  u16* qkvb = (u16*)ws;  ws += (size_t)8192 * 3072 * 2;
  u16* vtb = (u16*)ws;   ws += (size_t)64 * 64 * 2048 * 2;
  u16* yb = (u16*)ws;    ws += (size_t)8192 * 1024 * 2;

  cvt_bf16<<<8192, 256, 0, stream>>>(x, xb, 8192 * 1024);
  tconv<<<dim3(3072 / 64, 1024 / 64), 256, 0, stream>>>(w_attn, waT, 1024, 3072);
  tconv<<<dim3(1024 / 64, 1024 / 64), 256, 0, stream>>>(w_proj, wpT, 1024, 1024);
  gemm_bt<1><<<dim3(3072 / 128, 8192 / 128), 256, 0, stream>>>(xb, waT, b_attn, qkvb, 8192, 3072, 1024);
  vtrans<<<dim3(64, 32), 256, 0, stream>>>(qkvb, vtb);
  attn<<<dim3(64, 16), 256, 0, stream>>>(qkvb, vtb, yb);
  gemm_bt<0><<<dim3(1024 / 128, 8192 / 128), 256, 0, stream>>>(yb, wpT, b_proj, out, 8192, 1024, 1024);
}

// Round 7
// 316.347 us; speedup vs baseline: 1.6394x; 1.0052x over previous
//
#include <hip/hip_runtime.h>
#include <cstdint>
#include <cstddef>

typedef unsigned short u16;
typedef __bf16 bf16_t;
typedef bf16_t bf16x8 __attribute__((ext_vector_type(8)));
typedef float f32x4 __attribute__((ext_vector_type(4)));

__device__ __forceinline__ u16 f32_to_bf16(float f) {
  uint32_t u = __builtin_bit_cast(uint32_t, f);
  u += 0x7fffu + ((u >> 16) & 1u);   // RNE
  return (u16)(u >> 16);
}

// pack two f32 -> two bf16 in one u32 (round-half-up + v_perm_b32)
__device__ __forceinline__ uint32_t pack_bf16x2(float lo, float hi) {
  uint32_t a = __builtin_bit_cast(uint32_t, hi) + 0x8000u;
  uint32_t b = __builtin_bit_cast(uint32_t, lo) + 0x8000u;
  return __builtin_amdgcn_perm(a, b, 0x07060302u);
}

// async global->LDS, 16B per lane. LDS dest is wave-uniform base; HW adds lane*16.
__device__ __forceinline__ void gload_lds16(const void* g, void* l) {
  __builtin_amdgcn_global_load_lds(
      (const __attribute__((address_space(1))) unsigned int*)g,
      (__attribute__((address_space(3))) unsigned int*)l, 16, 0, 0);
}

// hand-rolled pipeline barrier: wait my DMA loads + LDS ops, then barrier.
__device__ __forceinline__ void vm_barrier() {
  asm volatile("s_waitcnt vmcnt(0) lgkmcnt(0)\n\ts_barrier" ::: "memory");
}

// ---------------- fp32 -> bf16 elementwise convert ----------------
__global__ void cvt_bf16(const float* __restrict__ in, u16* __restrict__ out, int n) {
  int i = (blockIdx.x * 256 + threadIdx.x) * 4;
  if (i < n) {
    float4 f = *(const float4*)(in + i);
    ushort4 o;
    o.x = f32_to_bf16(f.x); o.y = f32_to_bf16(f.y);
    o.z = f32_to_bf16(f.z); o.w = f32_to_bf16(f.w);
    *(ushort4*)(out + i) = o;
  }
}

// ---------------- fp32 [R][C] -> bf16 [C][R] transpose-convert ----------------
__global__ void tconv(const float* __restrict__ in, u16* __restrict__ out, int R, int C) {
  __shared__ u16 t[64][80];
  int tid = threadIdx.x;
  int cb = blockIdx.x * 64, rb = blockIdx.y * 64;
  int rr = tid >> 2, cg = (tid & 3) * 16;
  const float* ip = in + (size_t)(rb + rr) * C + cb + cg;
#pragma unroll
  for (int i = 0; i < 16; ++i) t[rr][cg + i] = f32_to_bf16(ip[i]);
  __syncthreads();
  int cc = tid >> 2, rg = (tid & 3) * 16;
  u16* op = out + (size_t)(cb + cc) * R + rb + rg;
  union { uint4 v[2]; u16 s[16]; } tmp;
#pragma unroll
  for (int i = 0; i < 16; ++i) tmp.s[i] = t[rg + i][cc];
  *(uint4*)op = tmp.v[0];
  *(uint4*)(op + 8) = tmp.v[1];
}

// ---------------- V slice of qkv (bf16) -> Vt [bh][d=64][t=2048] ----------------
__global__ void vtrans(const u16* __restrict__ qkvb, u16* __restrict__ vt) {
  __shared__ u16 t[64][80];
  int tid = threadIdx.x;
  int bh = blockIdx.x, tb = blockIdx.y * 64;
  int b = bh >> 4, h = bh & 15;
  int tt = tid >> 2, dg = (tid & 3) * 16;
  const u16* ip = qkvb + (size_t)(b * 2048 + tb + tt) * 3072 + 2048 + h * 64 + dg;
  union { uint4 v; u16 s[8]; } a0, a1;
  a0.v = *(const uint4*)ip;
  a1.v = *(const uint4*)(ip + 8);
#pragma unroll
  for (int i = 0; i < 8; ++i) { t[tt][dg + i] = a0.s[i]; t[tt][dg + 8 + i] = a1.s[i]; }
  __syncthreads();
  int dd = tid >> 2, tg = (tid & 3) * 16;
  u16* op = vt + (size_t)(bh * 64 + dd) * 2048 + tb + tg;
  union { uint4 v[2]; u16 s[16]; } tmp;
#pragma unroll
  for (int i = 0; i < 16; ++i) tmp.s[i] = t[tg + i][dd];
  *(uint4*)op = tmp.v[0];
  *(uint4*)(op + 8) = tmp.v[1];
}

// ---------------- bf16 GEMM: C[M,N] = A[M,K] * Bt[N,K]^T + bias ----------------
// 256x256 tile, BK=32, 512 threads (8 waves as 4x2; wave owns 64x128).
// Rationale (R6 post-mortem): the GEMM is staging-BW-bound (bytes through
// L3/L2 into LDS). 256^2 tile doubles FLOP per staged byte vs 128^2
// (786->384 MB for QKV). Double-buffered LDS + vmcnt barrier kept.
// Frags: 32 per tile (16 A + 16 B), 1 KB each, frag f = 16 rows x 32 k,
// lane L holds row (f*16 + L%16), k = (L/16)*8 .. +7  (MFMA A/B layout).
template <int OUT_BF16>
__global__ __launch_bounds__(512, 2) void gemm_bt(const u16* __restrict__ A,
                                                  const u16* __restrict__ Bt,
                                                  const float* __restrict__ bias,
                                                  void* __restrict__ Cout,
                                                  int M, int N, int K) {
  __shared__ __align__(16) u16 sAB[2][32 * 512];  // 64 KB
  const int tid = threadIdx.x;
  const int w = tid >> 6, L = tid & 63;
  const int quad = L >> 4, lc = L & 15;
  const int tileM = blockIdx.y * 256;
  const int tileN = blockIdx.x * 256;
  const int wr = w >> 1, wc = w & 1;   // wr in [0,4), wc in [0,2)

  // this wave's 4 staging fragments (fb = w*4+i)
  const u16* gsrc[4];
#pragma unroll
  for (int i = 0; i < 4; ++i) {
    int fb = w * 4 + i;
    if (fb < 16)
      gsrc[i] = A + (size_t)(tileM + fb * 16 + lc) * K + quad * 8;
    else
      gsrc[i] = Bt + (size_t)(tileN + (fb - 16) * 16 + lc) * K + quad * 8;
  }

  f32x4 acc[4][8] = {};

  // prologue: stage tile 0 into buf 0
#pragma unroll
  for (int i = 0; i < 4; ++i)
    gload_lds16(gsrc[i], &sAB[0][(w * 4 + i) * 512]);
  vm_barrier();

  int cur = 0;
  for (int kk = 0; kk < K; kk += 32) {
    const bool more = (kk + 32) < K;
    if (more) {
#pragma unroll
      for (int i = 0; i < 4; ++i)
        gload_lds16(gsrc[i] + kk + 32, &sAB[cur ^ 1][(w * 4 + i) * 512]);
    }
    const u16* base = sAB[cur];
    bf16x8 af[4], bfr[8];
#pragma unroll
    for (int t = 0; t < 4; ++t)
      af[t] = *(const bf16x8*)&base[(wr * 4 + t) * 512 + L * 8];
#pragma unroll
    for (int t = 0; t < 8; ++t)
      bfr[t] = *(const bf16x8*)&base[(16 + wc * 8 + t) * 512 + L * 8];
#pragma unroll
    for (int mi = 0; mi < 4; ++mi)
#pragma unroll
      for (int ni = 0; ni < 8; ++ni)
        acc[mi][ni] = __builtin_amdgcn_mfma_f32_16x16x32_bf16(af[mi], bfr[ni], acc[mi][ni], 0, 0, 0);
    if (more) {
      vm_barrier();
      cur ^= 1;
    }
  }

#pragma unroll
  for (int mi = 0; mi < 4; ++mi) {
    int rowb = tileM + wr * 64 + mi * 16 + quad * 4;
#pragma unroll
    for (int ni = 0; ni < 8; ++ni) {
      int col = tileN + wc * 128 + ni * 16 + lc;
      float bv = bias[col];
#pragma unroll
      for (int r = 0; r < 4; ++r) {
        float v = acc[mi][ni][r] + bv;
        if (OUT_BF16)
          ((u16*)Cout)[(size_t)(rowb + r) * N + col] = f32_to_bf16(v);
        else
          ((float*)Cout)[(size_t)(rowb + r) * N + col] = v;
      }
    }
  }
}

// ---------------- causal flash attention, S^T formulation ----------------
// S^T = K·Q^T (A=K frag, B=Q frag) -> C-layout row=tk, col=q(lc).
// O^T = V^T·P. Per-lane softmax sum; fixed-max softmax; diagonal-only mask;
// paired qt for uniform work. K/V double-buffered, vmcnt-barrier pipeline.
__global__ __launch_bounds__(256, 4) void attn(const u16* __restrict__ qkvb,
                                               const u16* __restrict__ vt,
                                               u16* __restrict__ yb) {
  __shared__ __align__(16) u16 kv[2][16 * 512];   // 32 KB
  __shared__ __align__(16) u16 pbuf[4][1024];     // 8 KB, per-wave P frags
  const int tid = threadIdx.x;
  const int w = tid >> 6, L = tid & 63;
  const int quad = L >> 4, lc = L & 15;
  const int bh = blockIdx.x;
  const int b = bh >> 4, h = bh & 15;
  const int pair = blockIdx.y;
  const float e_c = 0.18033688f;  // (1/sqrt(64)) * log2(e)
  u16* pb = (u16*)pbuf[w];
  const int fb0 = w * 4;

  for (int pass = 0; pass < 2; ++pass) {
    const int qt = pass ? (31 - pair) : pair;
    const int qbase = qt * 64;
    const int q_loc = w * 16 + lc;

    bf16x8 qf[2];
    {
      const u16* qp = qkvb + ((size_t)(b * 2048 + qbase + q_loc) * 3072 + h * 64 + quad * 8);
      qf[0] = *(const bf16x8*)qp;
      qf[1] = *(const bf16x8*)(qp + 32);
    }
    f32x4 o[4] = {};
    float lsum = 0.f;

    __syncthreads();  // pass boundary: prior-pass kv reads complete
#pragma unroll
    for (int i = 0; i < 4; ++i) {
      int fb = fb0 + i;
      if (fb < 8)
        gload_lds16(qkvb + ((size_t)(b * 2048 + (fb >> 1) * 16 + lc) * 3072 + 1024 + h * 64 + (fb & 1) * 32 + quad * 8),
                    &kv[0][fb * 512]);
      else {
        int f = fb - 8;
        gload_lds16(vt + ((size_t)(bh * 64 + (f >> 1) * 16 + lc) * 2048 + (f & 1) * 32 + quad * 8),
                    &kv[0][fb * 512]);
      }
    }
    vm_barrier();

    int cur = 0;
    for (int kb = 0; kb <= qbase; kb += 64) {
      const bool diag = (kb == qbase);
      const bool more = (kb + 64) <= qbase;
      if (more) {
        int kn = kb + 64;
#pragma unroll
        for (int i = 0; i < 4; ++i) {
          int fb = fb0 + i;
          if (fb < 8)
            gload_lds16(qkvb + ((size_t)(b * 2048 + kn + (fb >> 1) * 16 + lc) * 3072 + 1024 + h * 64 + (fb & 1) * 32 + quad * 8),
                        &kv[cur ^ 1][fb * 512]);
          else {
            int f = fb - 8;
            gload_lds16(vt + ((size_t)(bh * 64 + (f >> 1) * 16 + lc) * 2048 + kn + (f & 1) * 32 + quad * 8),
                        &kv[cur ^ 1][f * 512 + 8 * 512]);
          }
        }
      }
      const u16* base = kv[cur];

      // S^T[tk][q]
      f32x4 s[4];
#pragma unroll
      for (int nt = 0; nt < 4; ++nt) {
        s[nt] = (f32x4){0.f, 0.f, 0.f, 0.f};
#pragma unroll
        for (int ks = 0; ks < 2; ++ks) {
          bf16x8 kf = *(const bf16x8*)&base[(nt * 2 + ks) * 512 + L * 8];
          s[nt] = __builtin_amdgcn_mfma_f32_16x16x32_bf16(kf, qf[ks], s[nt], 0, 0, 0);
        }
      }

      // p = exp2(s*e_c); mask diagonal; accumulate per-lane l; pack to pbuf
#pragma unroll
      for (int nt = 0; nt < 4; ++nt) {
        float p0 = __builtin_amdgcn_exp2f(s[nt][0] * e_c);
        float p1 = __builtin_amdgcn_exp2f(s[nt][1] * e_c);
        float p2 = __builtin_amdgcn_exp2f(s[nt][2] * e_c);
        float p3 = __builtin_amdgcn_exp2f(s[nt][3] * e_c);
        if (diag) {
          int tk0 = nt * 16 + quad * 4;
          p0 = (tk0 + 0 > q_loc) ? 0.f : p0;
          p1 = (tk0 + 1 > q_loc) ? 0.f : p1;
          p2 = (tk0 + 2 > q_loc) ? 0.f : p2;
          p3 = (tk0 + 3 > q_loc) ? 0.f : p3;
        }
        lsum += (p0 + p1) + (p2 + p3);
        uint2 pk;
        pk.x = pack_bf16x2(p0, p1);
        pk.y = pack_bf16x2(p2, p3);
        int idx = (nt >> 1) * 512 + (((nt & 1) * 2 + (quad >> 1)) * 16 + lc) * 8 + (quad & 1) * 4;
        *(uint2*)&pb[idx] = pk;
      }

      // O^T += V^T · P
#pragma unroll
      for (int ks = 0; ks < 2; ++ks) {
        bf16x8 pf = *(const bf16x8*)&pb[ks * 512 + L * 8];
#pragma unroll
        for (int dt = 0; dt < 4; ++dt) {
          bf16x8 vf = *(const bf16x8*)&base[(8 + dt * 2 + ks) * 512 + L * 8];
          o[dt] = __builtin_amdgcn_mfma_f32_16x16x32_bf16(vf, pf, o[dt], 0, 0, 0);
        }
      }

      if (more) {
        vm_barrier();
        cur ^= 1;
      }
    }

    // l: sum the 4 quad partials for column q=lc
    lsum += __shfl_xor(lsum, 16);
    lsum += __shfl_xor(lsum, 32);
    float inv = 1.f / lsum;

    // store y[t=qbase+q_loc][h*64 + d], lane holds d = dt*16 + quad*4 + r
    {
      u16* yp = yb + (size_t)(b * 2048 + qbase + q_loc) * 1024 + h * 64 + quad * 4;
#pragma unroll
      for (int dt = 0; dt < 4; ++dt) {
        uint2 pk;
        pk.x = pack_bf16x2(o[dt][0] * inv, o[dt][1] * inv);
        pk.y = pack_bf16x2(o[dt][2] * inv, o[dt][3] * inv);
        *(uint2*)(yp + dt * 16) = pk;
      }
    }
  }
}

extern "C" void kernel_launch(void* const* d_in, const int* in_sizes, int n_in,
                              void* d_out, int out_size, void* d_ws, size_t ws_size,
                              hipStream_t stream) {
  const float* x = (const float*)d_in[0];
  const float* w_attn = (const float*)d_in[1];
  const float* b_attn = (const float*)d_in[2];
  const float* w_proj = (const float*)d_in[3];
  const float* b_proj = (const float*)d_in[4];
  float* out = (float*)d_out;

  char* ws = (char*)d_ws;
  u16* xb = (u16*)ws;    ws += (size_t)8192 * 1024 * 2;
  u16* waT = (u16*)ws;   ws += (size_t)3072 * 1024 * 2;
  u16* wpT = (u16*)ws;   ws += (size_t)1024 * 1024 * 2;
  u16* qkvb = (u16*)ws;  ws += (size_t)8192 * 3072 * 2;
  u16* vtb = (u16*)ws;   ws += (size_t)64 * 64 * 2048 * 2;
  u16* yb = (u16*)ws;    ws += (size_t)8192 * 1024 * 2;

  cvt_bf16<<<8192, 256, 0, stream>>>(x, xb, 8192 * 1024);
  tconv<<<dim3(3072 / 64, 1024 / 64), 256, 0, stream>>>(w_attn, waT, 1024, 3072);
  tconv<<<dim3(1024 / 64, 1024 / 64), 256, 0, stream>>>(w_proj, wpT, 1024, 1024);
  gemm_bt<1><<<dim3(3072 / 256, 8192 / 256), 512, 0, stream>>>(xb, waT, b_attn, qkvb, 8192, 3072, 1024);
  vtrans<<<dim3(64, 32), 256, 0, stream>>>(qkvb, vtb);
  attn<<<dim3(64, 16), 256, 0, stream>>>(qkvb, vtb, yb);
  gemm_bt<0><<<dim3(1024 / 256, 8192 / 256), 512, 0, stream>>>(yb, wpT, b_proj, out, 8192, 1024, 1024);
}